// Round 10
// baseline (1120.825 us; speedup 1.0000x reference)
//
#include <hip/hip_runtime.h>
#include <math.h>

#define TT 2048
#define BBATCH 256
#define DDIM 57
#define NROWS (BBATCH*TT)
#define NF 524288.0f
#define U 8
#define G 4              // slots per barrier epoch
#define NBUF 8           // 2*G h-buffers (producer epoch e, consumer e+1)
#define XROWS 64         // rows per xg0 block

#define K1 (-1.4426950408889634f)   // -log2(e)   : sigmoid rows (i,f,o)
#define K2 (-2.8853900817779268f)   // -2 log2(e) : tanh rows (g) and tanh(c)

__device__ __forceinline__ float bcastl(float v, int k) {
  return __uint_as_float((unsigned)__builtin_amdgcn_readlane((int)__float_as_uint(v), k));
}
__device__ __forceinline__ float rcpf(float x) { return __builtin_amdgcn_rcpf(x); }
__device__ __forceinline__ float exp2f_(float x) { return __builtin_amdgcn_exp2f(x); }

// quad_perm broadcast: all 4 lanes of each quad get lane (PAT&3)'s value.
template<int PAT>
__device__ __forceinline__ float quadb(float v) {
  return __int_as_float(__builtin_amdgcn_update_dpp(0, __float_as_int(v), PAT, 0xF, 0xF, true));
}

// R14 xg0 (unchanged): LDS-staged tile GEMM, 64 rows/block, uniform
// ds_read_b128 broadcasts, high occupancy so DS/VALU latency is TLP-hidden.
__global__ __launch_bounds__(256) void xg0_gemm_k(
    const float* __restrict__ x, const float* __restrict__ Wih,
    const float* __restrict__ bih, const float* __restrict__ bhh,
    float* __restrict__ xg0)
{
  const int tid = threadIdx.x;
  const int l   = tid & 63;          // output lane (scan layout)
  const int w   = tid >> 6;          // wave id: rows w*16 .. w*16+15
  const int g   = (l & 3) * 16 + (l >> 2);
  const float fac = ((l & 3) == 2) ? K2 : K1;

  __shared__ __align__(16) float xs[XROWS][60];

  float wv[60];
  #pragma unroll
  for (int d = 0; d < 60; ++d) wv[d] = (d < DDIM) ? fac * Wih[g*DDIM + d] : 0.f;
  const float bias = fac * (bih[g] + bhh[g]);

  const int rbase = blockIdx.x * XROWS;
  const float4* xsrc = (const float4*)(x + (size_t)rbase * DDIM); // 64*57*4 % 16 == 0: aligned
  #pragma unroll
  for (int it = 0; it < 4; ++it) {
    int i = tid + it*256;
    if (i < 912) {                     // 912 float4 = 3648 floats = 64 rows
      float4 v = xsrc[i];
      int f0 = 4*i;
      int r0 = f0/57, d0 = f0 - r0*57;            xs[r0][d0] = v.x;
      int f1 = f0+1, r1 = f1/57, d1 = f1 - r1*57; xs[r1][d1] = v.y;
      int f2 = f0+2, r2 = f2/57, d2 = f2 - r2*57; xs[r2][d2] = v.z;
      int f3 = f0+3, r3 = f3/57, d3 = f3 - r3*57; xs[r3][d3] = v.w;
    }
  }
  if (tid < 192) {                     // zero pad cols 57..59 (avoid NaN*0)
    int r = tid/3, c = 57 + (tid - 3*r);
    xs[r][c] = 0.f;
  }
  __syncthreads();

  #pragma unroll
  for (int rr = 0; rr < 16; ++rr) {
    const int r = w*16 + rr;           // wave-uniform -> ds_read broadcast
    const float4* xr = (const float4*)&xs[r][0];
    float a0 = bias, a1 = 0.f, a2 = 0.f, a3 = 0.f;
    #pragma unroll
    for (int i = 0; i < 15; ++i) {
      float4 v = xr[i];
      a0 += wv[4*i]   * v.x;
      a1 += wv[4*i+1] * v.y;
      a2 += wv[4*i+2] * v.z;
      a3 += wv[4*i+3] * v.w;
    }
    xg0[(size_t)(rbase + r)*64 + l] = (a0 + a1) + (a2 + a3);
  }
}

// R17 scan: TWO sequences per wave (ILP-paired chains). The serial LSTM
// chain leaves ~370 of ~470 cyc/step as dead stall (1 wave/SIMD, no TLP).
// Batches (2b,2b+1) are independent chains in the SAME wave; each step body
// runs A then B back-to-back, so B's ops issue inside A's latency shadow.
// Weights shared; state registers doubled (VGPR ~92->~170, 1 wave/SIMD has
// budget to 256). lengths sorted descending -> adjacent pair NS nearly
// equal, drain waste negligible. Epoch barriers G=4 unchanged from R14.
__global__ __launch_bounds__(192, 1) void lstm_scan_pipe_k(
    const float* __restrict__ xg0,
    const int*   __restrict__ lengths,
    const float* __restrict__ Whh0,
    const float* __restrict__ Wih1, const float* __restrict__ Whh1,
    const float* __restrict__ bih1, const float* __restrict__ bhh1,
    const float* __restrict__ Wih2, const float* __restrict__ Whh2,
    const float* __restrict__ bih2, const float* __restrict__ bhh2,
    float* __restrict__ h2buf, float* __restrict__ partial)
{
  const int tid  = threadIdx.x;
  const int wave = tid >> 6;
  const int lane = tid & 63;
  const int gt   = lane & 3;       // 0=i 1=f 2=g 3=o
  const int ch   = lane >> 2;      // channel 0..15
  const int g    = gt*16 + ch;     // weight row (PyTorch i,f,g,o blocks)
  const int b0   = blockIdx.x * 2;
  const int b1   = b0 + 1;
  const int len0 = lengths[b0];
  const int len1 = lengths[b1];
  const bool isg = (gt == 2);
  const float fac = isg ? K2 : K1;
  const float mg = isg ? (2.f*K2) : 1.f;   // g-gate act = K2*tanh (pre-scaled)
  const float ag = isg ? (-K2)    : 0.f;

  __shared__ float lds_h0A[NBUF][U][16];
  __shared__ float lds_h0B[NBUF][U][16];
  __shared__ float lds_h1A[NBUF][U][16];
  __shared__ float lds_h1B[NBUF][U][16];

  float wa[16], wb[16];
  float bias = 0.f;
  if (wave == 0) {
    #pragma unroll
    for (int k = 0; k < 16; ++k) { wb[k] = fac * Whh0[g*16 + k]; wa[k] = 0.f; }
  } else if (wave == 1) {
    #pragma unroll
    for (int k = 0; k < 16; ++k) { wa[k] = fac * Wih1[g*16 + k]; wb[k] = fac * Whh1[g*16 + k]; }
    bias = fac * (bih1[g] + bhh1[g]);
  } else {
    #pragma unroll
    for (int k = 0; k < 16; ++k) { wa[k] = fac * Wih2[g*16 + k]; wb[k] = fac * Whh2[g*16 + k]; }
    bias = fac * (bih2[g] + bhh2[g]);
  }

  float hsA = 0.f, csKA = 0.f, hsB = 0.f, csKB = 0.f;
  float sumA = 0.f, sqA = 0.f, sumB = 0.f, sqB = 0.f;
  const int baseA = b0*TT*64 + lane;
  const int baseB = b1*TT*64 + lane;
  float* __restrict__ h2rowA = h2buf + (size_t)b0*TT*16;
  float* __restrict__ h2rowB = h2buf + (size_t)b1*TT*16;

  auto lstm_update = [&](float dot, float& hs, float& csK) {
    float s   = rcpf(1.f + exp2f_(dot));
    float act = fmaf(s, mg, ag);          // sigmoid, or K2*tanh for g-gate
    float gi = quadb<0x00>(act);
    float gf = quadb<0x55>(act);
    float gg = quadb<0xAA>(act);          // = K2*tanh(g)
    float go = quadb<0xFF>(act);
    float go2 = go + go;                  // off critical path
    csK = fmaf(gf, csK, gg * gi);         // K2*(f*c + i*g)
    float r = rcpf(1.f + exp2f_(csK));
    hs = fmaf(go2, r, -go);               // go * tanh(c)
  };
  auto owndot = [&](float seed, float hs) {   // seed + Whh' . h_own
    float hb[16];                         // ALL broadcasts first (R8 lesson)
    #pragma unroll
    for (int k = 0; k < 16; ++k) hb[k] = bcastl(hs, 4*k);
    float a0 = seed, a1 = 0.f, a2 = 0.f, a3 = 0.f;
    #pragma unroll
    for (int k = 0; k < 16; k += 4) {
      a0 += wb[k]   * hb[k];
      a1 += wb[k+1] * hb[k+1];
      a2 += wb[k+2] * hb[k+2];
      a3 += wb[k+3] * hb[k+3];
    }
    return (a0 + a1) + (a2 + a3);
  };
  auto indot = [&](const float* hin) {    // bias + Wih' . hin (register vector)
    float a0 = bias, a1 = 0.f, a2 = 0.f, a3 = 0.f;
    #pragma unroll
    for (int k = 0; k < 16; k += 4) {
      a0 += wa[k]   * hin[k];
      a1 += wa[k+1] * hin[k+1];
      a2 += wa[k+2] * hin[k+2];
      a3 += wa[k+3] * hin[k+3];
    }
    return (a0 + a1) + (a2 + a3);
  };
  auto ldhin = [&](const float* src, float* hin) {
    const float4* hp = (const float4*)src;
    float4 h0v = hp[0], h1v = hp[1], h2v = hp[2], h3v = hp[3];
    hin[0]=h0v.x; hin[1]=h0v.y; hin[2]=h0v.z; hin[3]=h0v.w;
    hin[4]=h1v.x; hin[5]=h1v.y; hin[6]=h1v.z; hin[7]=h1v.w;
    hin[8]=h2v.x; hin[9]=h2v.y; hin[10]=h2v.z; hin[11]=h2v.w;
    hin[12]=h3v.x; hin[13]=h3v.y; hin[14]=h3v.z; hin[15]=h3v.w;
  };

  const int NS0 = (len0 + U - 1) / U;
  const int NS1 = (len1 + U - 1) / U;     // NS1 <= NS0 (sorted lengths)
  const int E   = (NS0 + 2*G - 1) / G + 1;

  float curA[U], nxtA[U], curB[U], nxtB[U];
  if (wave == 0) {
    #pragma unroll
    for (int j = 0; j < U; ++j) { curA[j] = xg0[baseA + j*64]; curB[j] = xg0[baseB + j*64]; }
    #pragma unroll
    for (int j = 0; j < U; ++j) {
      int ip = U + j; ip = ip > TT-1 ? TT-1 : ip;
      nxtA[j] = xg0[baseA + ip*64]; nxtB[j] = xg0[baseB + ip*64];
    }
  }

  for (int e = 0; e < E; ++e) {
    #pragma unroll 1
    for (int q = 0; q < G; ++q) {
      const int tw = G*e + q;
      if (wave == 0) {
        const int t = tw;
        const bool okA = (t < NS0), okB = (t < NS1);
        if (okA) {
          const int p = t & (NBUF-1);
          float ldA[U], ldB[U];
          #pragma unroll
          for (int j = 0; j < U; ++j) {
            int ip = (t + 2)*U + j; ip = ip > TT-1 ? TT-1 : ip;
            ldA[j] = xg0[baseA + ip*64];
            if (okB) ldB[j] = xg0[baseB + ip*64];
          }
          #pragma unroll
          for (int j = 0; j < U; ++j) {   // A-step then B-step: independent
            lstm_update(owndot(curA[j], hsA), hsA, csKA);   // chains, B fills
            if (gt == 0) lds_h0A[p][j][ch] = hsA;           // A's stalls
            if (okB) {
              lstm_update(owndot(curB[j], hsB), hsB, csKB);
              if (gt == 0) lds_h0B[p][j][ch] = hsB;
            }
          }
          #pragma unroll
          for (int j = 0; j < U; ++j) {
            curA[j] = nxtA[j]; nxtA[j] = ldA[j];
            if (okB) { curB[j] = nxtB[j]; nxtB[j] = ldB[j]; }
          }
        }
      } else if (wave == 1) {
        const int t = tw - G;
        const bool okA = (t >= 0 && t < NS0), okB = (t >= 0 && t < NS1);
        if (okA) {
          const int p = t & (NBUF-1);
          float xinA[U], xinB[U];
          #pragma unroll
          for (int j = 0; j < U; ++j) {   // ALL input-dots up front, off-chain
            float hin[16];
            ldhin(&lds_h0A[p][j][0], hin);
            xinA[j] = indot(hin);
            if (okB) { ldhin(&lds_h0B[p][j][0], hin); xinB[j] = indot(hin); }
          }
          #pragma unroll
          for (int j = 0; j < U; ++j) {
            lstm_update(owndot(xinA[j], hsA), hsA, csKA);
            if (gt == 0) lds_h1A[p][j][ch] = hsA;
            if (okB) {
              lstm_update(owndot(xinB[j], hsB), hsB, csKB);
              if (gt == 0) lds_h1B[p][j][ch] = hsB;
            }
          }
        }
      } else {
        const int t = tw - 2*G;
        const bool okA = (t >= 0 && t < NS0), okB = (t >= 0 && t < NS1);
        if (okA) {
          const int p = t & (NBUF-1);
          float xinA[U], xinB[U];
          #pragma unroll
          for (int j = 0; j < U; ++j) {
            float hin[16];
            ldhin(&lds_h1A[p][j][0], hin);
            xinA[j] = indot(hin);
            if (okB) { ldhin(&lds_h1B[p][j][0], hin); xinB[j] = indot(hin); }
          }
          #pragma unroll
          for (int j = 0; j < U; ++j) {
            lstm_update(owndot(xinA[j], hsA), hsA, csKA);
            const int ts = t*U + j;
            if (ts < len0) {
              if (gt == 0) h2rowA[ts*16 + ch] = hsA;
              sumA += hsA; sqA += hsA*hsA;
            }
            if (okB) {
              lstm_update(owndot(xinB[j], hsB), hsB, csKB);
              if (ts < len1) {
                if (gt == 0) h2rowB[ts*16 + ch] = hsB;
                sumB += hsB; sqB += hsB*hsB;
              }
            }
          }
        }
      }
    }
    __syncthreads();
  }

  for (int idx = len0*16 + tid; idx < TT*16; idx += 192) h2rowA[idx] = 0.f;
  for (int idx = len1*16 + tid; idx < TT*16; idx += 192) h2rowB[idx] = 0.f;

  if (wave == 2 && gt == 0) {            // non-atomic per-block partials
    partial[b0*32 + ch]      = sumA;
    partial[b0*32 + 16 + ch] = sqA;
    partial[b1*32 + ch]      = sumB;
    partial[b1*32 + 16 + ch] = sqB;
  }
}

// R16 finalize (unchanged): every block redundantly reduces the 8192
// partials (32KB, L2-broadcast-friendly) -> BN+FC coef in LDS -> transforms
// its 256 h2 rows.
__global__ __launch_bounds__(256) void finalize_k(
    const float* __restrict__ partial,
    const float* __restrict__ gamma, const float* __restrict__ beta,
    const float* __restrict__ fcw, const float* __restrict__ fcb,
    const float* __restrict__ h2buf, float* __restrict__ out)
{
  const int tid = threadIdx.x;
  __shared__ float red[8][32];
  __shared__ float coef_s[68];

  const int c = tid & 31, chunk = tid >> 5;   // 8 chunks x 32 channels
  float acc = 0.f;
  #pragma unroll 4
  for (int bb = chunk; bb < BBATCH; bb += 8)
    acc += partial[bb*32 + c];
  red[chunk][c] = acc;
  __syncthreads();
  if (tid < 32) {
    float tot = 0.f;
    #pragma unroll
    for (int k = 0; k < 8; ++k) tot += red[k][tid];
    red[0][tid] = tot;
  }
  __syncthreads();
  if (tid < 64) {
    const int o = tid >> 4, c2 = tid & 15;
    const float inv_n = 1.0f / NF;
    float mean = red[0][c2] * inv_n;
    float var  = red[0][16 + c2] * inv_n - mean*mean;
    float s  = gamma[c2] * rsqrtf(var + 1e-5f);
    float tb = beta[c2] - mean * s;
    float woc = fcw[o*16 + c2];
    coef_s[tid] = s * woc;
    float term = tb * woc;
    #pragma unroll
    for (int off = 1; off < 16; off <<= 1) term += __shfl_xor(term, off, 16);
    if (c2 == 0) coef_s[64 + o] = fcb[o] + term;
  }
  __syncthreads();

  const int r = blockIdx.x * 256 + tid;
  const float4* hp = (const float4*)(h2buf + (size_t)r * 16);
  float4 v0 = hp[0], v1 = hp[1], v2 = hp[2], v3 = hp[3];
  float hv[16] = {v0.x,v0.y,v0.z,v0.w, v1.x,v1.y,v1.z,v1.w,
                  v2.x,v2.y,v2.z,v2.w, v3.x,v3.y,v3.z,v3.w};
  float4 o4;
  float* op = &o4.x;
  #pragma unroll
  for (int o = 0; o < 4; ++o) {
    float a = coef_s[64 + o];
    #pragma unroll
    for (int c3 = 0; c3 < 16; ++c3) a += coef_s[o*16 + c3] * hv[c3];
    op[o] = a;
  }
  ((float4*)out)[r] = o4;
}

extern "C" void kernel_launch(void* const* d_in, const int* in_sizes, int n_in,
                              void* d_out, int out_size, void* d_ws, size_t ws_size,
                              hipStream_t stream)
{
  const float* x     = (const float*)d_in[0];
  const int* lengths = (const int*)d_in[1];
  const float* W_ih0 = (const float*)d_in[2];
  const float* W_hh0 = (const float*)d_in[3];
  const float* b_ih0 = (const float*)d_in[4];
  const float* b_hh0 = (const float*)d_in[5];
  const float* W_ih1 = (const float*)d_in[6];
  const float* W_hh1 = (const float*)d_in[7];
  const float* b_ih1 = (const float*)d_in[8];
  const float* b_hh1 = (const float*)d_in[9];
  const float* W_ih2 = (const float*)d_in[10];
  const float* W_hh2 = (const float*)d_in[11];
  const float* b_ih2 = (const float*)d_in[12];
  const float* b_hh2 = (const float*)d_in[13];
  const float* gamma = (const float*)d_in[14];
  const float* beta  = (const float*)d_in[15];
  const float* fcw   = (const float*)d_in[16];
  const float* fcb   = (const float*)d_in[17];
  float* out = (float*)d_out;

  float* ws      = (float*)d_ws;
  float* xg0     = ws;                        // B*T*64 floats (128 MB)
  float* h2      = ws + 33554432;             // B*T*16 floats (32 MB)
  float* partial = ws + 33554432 + 8388608;   // 256*32 floats

  hipLaunchKernelGGL(xg0_gemm_k, dim3(NROWS/XROWS), dim3(256), 0, stream,
                     x, W_ih0, b_ih0, b_hh0, xg0);
  hipLaunchKernelGGL(lstm_scan_pipe_k, dim3(BBATCH/2), dim3(192), 0, stream,
                     xg0, lengths, W_hh0, W_ih1, W_hh1, b_ih1, b_hh1,
                     W_ih2, W_hh2, b_ih2, b_hh2, h2, partial);
  hipLaunchKernelGGL(finalize_k, dim3(2048), dim3(256), 0, stream,
                     partial, gamma, beta, fcw, fcb, h2, out);
}

// Round 11
// 976.391 us; speedup vs baseline: 1.1479x; 1.1479x over previous
//
#include <hip/hip_runtime.h>
#include <math.h>

#define TT 2048
#define BBATCH 256
#define DDIM 57
#define NROWS (BBATCH*TT)
#define NF 524288.0f
#define U 8
#define G 4              // slots per barrier epoch
#define NBUF 8           // 2*G h-buffers (producer epoch e, consumer e+1)
#define XROWS 64         // rows per xg0 block

#define K1 (-1.4426950408889634f)   // -log2(e)   : sigmoid rows (i,f,o)
#define K2 (-2.8853900817779268f)   // -2 log2(e) : tanh rows (g) and tanh(c)

__device__ __forceinline__ float bcastl(float v, int k) {
  return __uint_as_float((unsigned)__builtin_amdgcn_readlane((int)__float_as_uint(v), k));
}
__device__ __forceinline__ float rcpf(float x) { return __builtin_amdgcn_rcpf(x); }
__device__ __forceinline__ float exp2f_(float x) { return __builtin_amdgcn_exp2f(x); }

// quad_perm broadcast: all 4 lanes of each quad get lane (PAT&3)'s value.
template<int PAT>
__device__ __forceinline__ float quadb(float v) {
  return __int_as_float(__builtin_amdgcn_update_dpp(0, __float_as_int(v), PAT, 0xF, 0xF, true));
}

// R14 xg0 (unchanged): LDS-staged tile GEMM, 64 rows/block, uniform
// ds_read_b128 broadcasts, high occupancy so DS/VALU latency is TLP-hidden.
__global__ __launch_bounds__(256) void xg0_gemm_k(
    const float* __restrict__ x, const float* __restrict__ Wih,
    const float* __restrict__ bih, const float* __restrict__ bhh,
    float* __restrict__ xg0)
{
  const int tid = threadIdx.x;
  const int l   = tid & 63;          // output lane (scan layout)
  const int w   = tid >> 6;          // wave id: rows w*16 .. w*16+15
  const int g   = (l & 3) * 16 + (l >> 2);
  const float fac = ((l & 3) == 2) ? K2 : K1;

  __shared__ __align__(16) float xs[XROWS][60];

  float wv[60];
  #pragma unroll
  for (int d = 0; d < 60; ++d) wv[d] = (d < DDIM) ? fac * Wih[g*DDIM + d] : 0.f;
  const float bias = fac * (bih[g] + bhh[g]);

  const int rbase = blockIdx.x * XROWS;
  const float4* xsrc = (const float4*)(x + (size_t)rbase * DDIM); // 64*57*4 % 16 == 0: aligned
  #pragma unroll
  for (int it = 0; it < 4; ++it) {
    int i = tid + it*256;
    if (i < 912) {                     // 912 float4 = 3648 floats = 64 rows
      float4 v = xsrc[i];
      int f0 = 4*i;
      int r0 = f0/57, d0 = f0 - r0*57;            xs[r0][d0] = v.x;
      int f1 = f0+1, r1 = f1/57, d1 = f1 - r1*57; xs[r1][d1] = v.y;
      int f2 = f0+2, r2 = f2/57, d2 = f2 - r2*57; xs[r2][d2] = v.z;
      int f3 = f0+3, r3 = f3/57, d3 = f3 - r3*57; xs[r3][d3] = v.w;
    }
  }
  if (tid < 192) {                     // zero pad cols 57..59 (avoid NaN*0)
    int r = tid/3, c = 57 + (tid - 3*r);
    xs[r][c] = 0.f;
  }
  __syncthreads();

  #pragma unroll
  for (int rr = 0; rr < 16; ++rr) {
    const int r = w*16 + rr;           // wave-uniform -> ds_read broadcast
    const float4* xr = (const float4*)&xs[r][0];
    float a0 = bias, a1 = 0.f, a2 = 0.f, a3 = 0.f;
    #pragma unroll
    for (int i = 0; i < 15; ++i) {
      float4 v = xr[i];
      a0 += wv[4*i]   * v.x;
      a1 += wv[4*i+1] * v.y;
      a2 += wv[4*i+2] * v.z;
      a3 += wv[4*i+3] * v.w;
    }
    xg0[(size_t)(rbase + r)*64 + l] = (a0 + a1) + (a2 + a3);
  }
}

// R18 scan: paired chains, BRANCH-FREE step bodies. R17's pairing failed
// (zero overlap, exactly 2x serial) because every B-step sat in its own
// basic block (`if (okB)` s_cbranch) and the machine scheduler can't
// interleave across blocks; divergent `if(gt==0)` stores chopped it more.
// Fix: (1) B computes unconditionally wherever A does (NS1<=NS0; xg0 valid
// for all TT rows; garbage past len1 never stored); (2) hs saved per-j to
// statically-indexed register arrays, ALL divergent stores hoisted after
// the chain loop -> the 8-step paired loop is one straight-line block and
// the scheduler interleaves the two independent chains; (3) wave2 accums
// branch-free via value-select.
__global__ __launch_bounds__(192, 1) void lstm_scan_pipe_k(
    const float* __restrict__ xg0,
    const int*   __restrict__ lengths,
    const float* __restrict__ Whh0,
    const float* __restrict__ Wih1, const float* __restrict__ Whh1,
    const float* __restrict__ bih1, const float* __restrict__ bhh1,
    const float* __restrict__ Wih2, const float* __restrict__ Whh2,
    const float* __restrict__ bih2, const float* __restrict__ bhh2,
    float* __restrict__ h2buf, float* __restrict__ partial)
{
  const int tid  = threadIdx.x;
  const int wave = tid >> 6;
  const int lane = tid & 63;
  const int gt   = lane & 3;       // 0=i 1=f 2=g 3=o
  const int ch   = lane >> 2;      // channel 0..15
  const int g    = gt*16 + ch;     // weight row (PyTorch i,f,g,o blocks)
  const int b0   = blockIdx.x * 2;
  const int b1   = b0 + 1;
  const int len0 = lengths[b0];
  const int len1 = lengths[b1];
  const bool isg = (gt == 2);
  const float fac = isg ? K2 : K1;
  const float mg = isg ? (2.f*K2) : 1.f;   // g-gate act = K2*tanh (pre-scaled)
  const float ag = isg ? (-K2)    : 0.f;

  __shared__ float lds_h0A[NBUF][U][16];
  __shared__ float lds_h0B[NBUF][U][16];
  __shared__ float lds_h1A[NBUF][U][16];
  __shared__ float lds_h1B[NBUF][U][16];

  float wa[16], wb[16];
  float bias = 0.f;
  if (wave == 0) {
    #pragma unroll
    for (int k = 0; k < 16; ++k) { wb[k] = fac * Whh0[g*16 + k]; wa[k] = 0.f; }
  } else if (wave == 1) {
    #pragma unroll
    for (int k = 0; k < 16; ++k) { wa[k] = fac * Wih1[g*16 + k]; wb[k] = fac * Whh1[g*16 + k]; }
    bias = fac * (bih1[g] + bhh1[g]);
  } else {
    #pragma unroll
    for (int k = 0; k < 16; ++k) { wa[k] = fac * Wih2[g*16 + k]; wb[k] = fac * Whh2[g*16 + k]; }
    bias = fac * (bih2[g] + bhh2[g]);
  }

  float hsA = 0.f, csKA = 0.f, hsB = 0.f, csKB = 0.f;
  float sumA = 0.f, sqA = 0.f, sumB = 0.f, sqB = 0.f;
  const int baseA = b0*TT*64 + lane;
  const int baseB = b1*TT*64 + lane;
  float* __restrict__ h2rowA = h2buf + (size_t)b0*TT*16;
  float* __restrict__ h2rowB = h2buf + (size_t)b1*TT*16;

  // One straight-line paired step: dot(A)+dot(B) broadcasts first, then both
  // FMA trees, then both activation chains. No branches anywhere inside.
  auto pairstep = [&](float seedA, float seedB) {
    float hbA[16], hbB[16];
    #pragma unroll
    for (int k = 0; k < 16; ++k) { hbA[k] = bcastl(hsA, 4*k); hbB[k] = bcastl(hsB, 4*k); }
    float a0 = seedA, a1 = 0.f, a2 = 0.f, a3 = 0.f;
    float c0 = seedB, c1 = 0.f, c2 = 0.f, c3 = 0.f;
    #pragma unroll
    for (int k = 0; k < 16; k += 4) {
      a0 += wb[k]   * hbA[k];
      a1 += wb[k+1] * hbA[k+1];
      a2 += wb[k+2] * hbA[k+2];
      a3 += wb[k+3] * hbA[k+3];
      c0 += wb[k]   * hbB[k];
      c1 += wb[k+1] * hbB[k+1];
      c2 += wb[k+2] * hbB[k+2];
      c3 += wb[k+3] * hbB[k+3];
    }
    float dotA = (a0 + a1) + (a2 + a3);
    float dotB = (c0 + c1) + (c2 + c3);
    float sA   = rcpf(1.f + exp2f_(dotA));
    float sB   = rcpf(1.f + exp2f_(dotB));
    float actA = fmaf(sA, mg, ag);
    float actB = fmaf(sB, mg, ag);
    float giA = quadb<0x00>(actA), giB = quadb<0x00>(actB);
    float gfA = quadb<0x55>(actA), gfB = quadb<0x55>(actB);
    float ggA = quadb<0xAA>(actA), ggB = quadb<0xAA>(actB);
    float goA = quadb<0xFF>(actA), goB = quadb<0xFF>(actB);
    float go2A = goA + goA, go2B = goB + goB;
    csKA = fmaf(gfA, csKA, ggA * giA);
    csKB = fmaf(gfB, csKB, ggB * giB);
    float rA = rcpf(1.f + exp2f_(csKA));
    float rB = rcpf(1.f + exp2f_(csKB));
    hsA = fmaf(go2A, rA, -goA);
    hsB = fmaf(go2B, rB, -goB);
  };
  auto indot = [&](const float* hin) {    // bias + Wih' . hin (register vector)
    float a0 = bias, a1 = 0.f, a2 = 0.f, a3 = 0.f;
    #pragma unroll
    for (int k = 0; k < 16; k += 4) {
      a0 += wa[k]   * hin[k];
      a1 += wa[k+1] * hin[k+1];
      a2 += wa[k+2] * hin[k+2];
      a3 += wa[k+3] * hin[k+3];
    }
    return (a0 + a1) + (a2 + a3);
  };
  auto ldhin = [&](const float* src, float* hin) {
    const float4* hp = (const float4*)src;
    float4 h0v = hp[0], h1v = hp[1], h2v = hp[2], h3v = hp[3];
    hin[0]=h0v.x; hin[1]=h0v.y; hin[2]=h0v.z; hin[3]=h0v.w;
    hin[4]=h1v.x; hin[5]=h1v.y; hin[6]=h1v.z; hin[7]=h1v.w;
    hin[8]=h2v.x; hin[9]=h2v.y; hin[10]=h2v.z; hin[11]=h2v.w;
    hin[12]=h3v.x; hin[13]=h3v.y; hin[14]=h3v.z; hin[15]=h3v.w;
  };

  const int NS0 = (len0 + U - 1) / U;     // NS1 <= NS0 (sorted lengths);
  const int E   = (NS0 + 2*G - 1) / G + 1; // B computed unconditionally.

  float curA[U], nxtA[U], curB[U], nxtB[U];
  if (wave == 0) {
    #pragma unroll
    for (int j = 0; j < U; ++j) { curA[j] = xg0[baseA + j*64]; curB[j] = xg0[baseB + j*64]; }
    #pragma unroll
    for (int j = 0; j < U; ++j) {
      int ip = U + j; ip = ip > TT-1 ? TT-1 : ip;
      nxtA[j] = xg0[baseA + ip*64]; nxtB[j] = xg0[baseB + ip*64];
    }
  }

  for (int e = 0; e < E; ++e) {
    #pragma unroll 1
    for (int q = 0; q < G; ++q) {
      const int tw = G*e + q;
      if (wave == 0) {
        const int t = tw;
        if (t < NS0) {
          const int p = t & (NBUF-1);
          float ldA[U], ldB[U];
          #pragma unroll
          for (int j = 0; j < U; ++j) {
            int ip = (t + 2)*U + j; ip = ip > TT-1 ? TT-1 : ip;
            ldA[j] = xg0[baseA + ip*64];
            ldB[j] = xg0[baseB + ip*64];
          }
          float hvA[U], hvB[U];
          #pragma unroll
          for (int j = 0; j < U; ++j) {   // straight-line paired chain
            pairstep(curA[j], curB[j]);
            hvA[j] = hsA; hvB[j] = hsB;
          }
          if (gt == 0) {                  // all divergent stores after chain
            #pragma unroll
            for (int j = 0; j < U; ++j) {
              lds_h0A[p][j][ch] = hvA[j];
              lds_h0B[p][j][ch] = hvB[j];
            }
          }
          #pragma unroll
          for (int j = 0; j < U; ++j) {
            curA[j] = nxtA[j]; nxtA[j] = ldA[j];
            curB[j] = nxtB[j]; nxtB[j] = ldB[j];
          }
        }
      } else if (wave == 1) {
        const int t = tw - G;
        if (t >= 0 && t < NS0) {
          const int p = t & (NBUF-1);
          float xinA[U], xinB[U];
          #pragma unroll
          for (int j = 0; j < U; ++j) {   // ALL input-dots up front, off-chain
            float hin[16];
            ldhin(&lds_h0A[p][j][0], hin);
            xinA[j] = indot(hin);
            ldhin(&lds_h0B[p][j][0], hin);
            xinB[j] = indot(hin);
          }
          float hvA[U], hvB[U];
          #pragma unroll
          for (int j = 0; j < U; ++j) {
            pairstep(xinA[j], xinB[j]);
            hvA[j] = hsA; hvB[j] = hsB;
          }
          if (gt == 0) {
            #pragma unroll
            for (int j = 0; j < U; ++j) {
              lds_h1A[p][j][ch] = hvA[j];
              lds_h1B[p][j][ch] = hvB[j];
            }
          }
        }
      } else {
        const int t = tw - 2*G;
        if (t >= 0 && t < NS0) {
          const int p = t & (NBUF-1);
          float xinA[U], xinB[U];
          #pragma unroll
          for (int j = 0; j < U; ++j) {
            float hin[16];
            ldhin(&lds_h1A[p][j][0], hin);
            xinA[j] = indot(hin);
            ldhin(&lds_h1B[p][j][0], hin);
            xinB[j] = indot(hin);
          }
          float hvA[U], hvB[U];
          #pragma unroll
          for (int j = 0; j < U; ++j) {
            pairstep(xinA[j], xinB[j]);
            const int ts = t*U + j;
            float vA = (ts < len0) ? hsA : 0.f;   // branch-free accumulate
            float vB = (ts < len1) ? hsB : 0.f;
            sumA += vA; sqA += vA*vA;
            sumB += vB; sqB += vB*vB;
            hvA[j] = hsA; hvB[j] = hsB;
          }
          if (gt == 0) {                  // guarded stores after the chain
            #pragma unroll
            for (int j = 0; j < U; ++j) {
              const int ts = t*U + j;
              if (ts < len0) h2rowA[ts*16 + ch] = hvA[j];
              if (ts < len1) h2rowB[ts*16 + ch] = hvB[j];
            }
          }
        }
      }
    }
    __syncthreads();
  }

  for (int idx = len0*16 + tid; idx < TT*16; idx += 192) h2rowA[idx] = 0.f;
  for (int idx = len1*16 + tid; idx < TT*16; idx += 192) h2rowB[idx] = 0.f;

  if (wave == 2 && gt == 0) {            // non-atomic per-block partials
    partial[b0*32 + ch]      = sumA;
    partial[b0*32 + 16 + ch] = sqA;
    partial[b1*32 + ch]      = sumB;
    partial[b1*32 + 16 + ch] = sqB;
  }
}

// R16 finalize (unchanged): every block redundantly reduces the 8192
// partials (32KB, L2-broadcast-friendly) -> BN+FC coef in LDS -> transforms
// its 256 h2 rows.
__global__ __launch_bounds__(256) void finalize_k(
    const float* __restrict__ partial,
    const float* __restrict__ gamma, const float* __restrict__ beta,
    const float* __restrict__ fcw, const float* __restrict__ fcb,
    const float* __restrict__ h2buf, float* __restrict__ out)
{
  const int tid = threadIdx.x;
  __shared__ float red[8][32];
  __shared__ float coef_s[68];

  const int c = tid & 31, chunk = tid >> 5;   // 8 chunks x 32 channels
  float acc = 0.f;
  #pragma unroll 4
  for (int bb = chunk; bb < BBATCH; bb += 8)
    acc += partial[bb*32 + c];
  red[chunk][c] = acc;
  __syncthreads();
  if (tid < 32) {
    float tot = 0.f;
    #pragma unroll
    for (int k = 0; k < 8; ++k) tot += red[k][tid];
    red[0][tid] = tot;
  }
  __syncthreads();
  if (tid < 64) {
    const int o = tid >> 4, c2 = tid & 15;
    const float inv_n = 1.0f / NF;
    float mean = red[0][c2] * inv_n;
    float var  = red[0][16 + c2] * inv_n - mean*mean;
    float s  = gamma[c2] * rsqrtf(var + 1e-5f);
    float tb = beta[c2] - mean * s;
    float woc = fcw[o*16 + c2];
    coef_s[tid] = s * woc;
    float term = tb * woc;
    #pragma unroll
    for (int off = 1; off < 16; off <<= 1) term += __shfl_xor(term, off, 16);
    if (c2 == 0) coef_s[64 + o] = fcb[o] + term;
  }
  __syncthreads();

  const int r = blockIdx.x * 256 + tid;
  const float4* hp = (const float4*)(h2buf + (size_t)r * 16);
  float4 v0 = hp[0], v1 = hp[1], v2 = hp[2], v3 = hp[3];
  float hv[16] = {v0.x,v0.y,v0.z,v0.w, v1.x,v1.y,v1.z,v1.w,
                  v2.x,v2.y,v2.z,v2.w, v3.x,v3.y,v3.z,v3.w};
  float4 o4;
  float* op = &o4.x;
  #pragma unroll
  for (int o = 0; o < 4; ++o) {
    float a = coef_s[64 + o];
    #pragma unroll
    for (int c3 = 0; c3 < 16; ++c3) a += coef_s[o*16 + c3] * hv[c3];
    op[o] = a;
  }
  ((float4*)out)[r] = o4;
}

extern "C" void kernel_launch(void* const* d_in, const int* in_sizes, int n_in,
                              void* d_out, int out_size, void* d_ws, size_t ws_size,
                              hipStream_t stream)
{
  const float* x     = (const float*)d_in[0];
  const int* lengths = (const int*)d_in[1];
  const float* W_ih0 = (const float*)d_in[2];
  const float* W_hh0 = (const float*)d_in[3];
  const float* b_ih0 = (const float*)d_in[4];
  const float* b_hh0 = (const float*)d_in[5];
  const float* W_ih1 = (const float*)d_in[6];
  const float* W_hh1 = (const float*)d_in[7];
  const float* b_ih1 = (const float*)d_in[8];
  const float* b_hh1 = (const float*)d_in[9];
  const float* W_ih2 = (const float*)d_in[10];
  const float* W_hh2 = (const float*)d_in[11];
  const float* b_ih2 = (const float*)d_in[12];
  const float* b_hh2 = (const float*)d_in[13];
  const float* gamma = (const float*)d_in[14];
  const float* beta  = (const float*)d_in[15];
  const float* fcw   = (const float*)d_in[16];
  const float* fcb   = (const float*)d_in[17];
  float* out = (float*)d_out;

  float* ws      = (float*)d_ws;
  float* xg0     = ws;                        // B*T*64 floats (128 MB)
  float* h2      = ws + 33554432;             // B*T*16 floats (32 MB)
  float* partial = ws + 33554432 + 8388608;   // 256*32 floats

  hipLaunchKernelGGL(xg0_gemm_k, dim3(NROWS/XROWS), dim3(256), 0, stream,
                     x, W_ih0, b_ih0, b_hh0, xg0);
  hipLaunchKernelGGL(lstm_scan_pipe_k, dim3(BBATCH/2), dim3(192), 0, stream,
                     xg0, lengths, W_hh0, W_ih1, W_hh1, b_ih1, b_hh1,
                     W_ih2, W_hh2, b_ih2, b_hh2, h2, partial);
  hipLaunchKernelGGL(finalize_k, dim3(2048), dim3(256), 0, stream,
                     partial, gamma, beta, fcw, fcb, h2, out);
}